// Round 1
// baseline (509.387 us; speedup 1.0000x reference)
//
#include <hip/hip_runtime.h>

// OSNAP sketch: out[n,f] = sum_d x[n,d] * P[f,d]
// x: [16384, 4096] f32, P: [8192, 4096] f32 with exactly 4 nonzeros (+-0.5) per column.
// Strategy: extract sparse structure of P into row-CSR in d_ws, then gather.

#define D_IN        4096
#define D_FEAT      8192
#define N_TOTAL     16384
#define CAP         24      // max nnz per output row (Poisson(2); P(>=24) ~ 1e-13)
#define NR          4       // x-rows per block in the gather kernel

// ---------------- ws layout (bytes) ----------------
// col_f   : int  [D_IN*4]        @ 0        (64 KB)
// col_v   : float[D_IN*4]        @ 65536    (64 KB)
// col_cnt : int  [D_IN]          @ 131072   (16 KB)
// row_cnt : int  [D_FEAT]        @ 147456   (32 KB)
// row_ent : int2 [D_FEAT*CAP]    @ 180224   (1.5 MB)   .x=d  .y=bits(val)
// total ~1.72 MB

__global__ void k_zero(int* __restrict__ col_cnt, int* __restrict__ row_cnt) {
    int t = blockIdx.x * blockDim.x + threadIdx.x;
    if (t < D_IN)   col_cnt[t] = 0;
    if (t < D_FEAT) row_cnt[t] = 0;
}

// Full-bandwidth scan of P; append nonzeros to per-column lists (order fixed later).
__global__ void k_scan(const float4* __restrict__ p4,
                       int* __restrict__ col_cnt,
                       int* __restrict__ col_f,
                       float* __restrict__ col_v) {
    const long total = (long)D_FEAT * D_IN / 4;
    for (long q = (long)blockIdx.x * blockDim.x + threadIdx.x; q < total;
         q += (long)gridDim.x * blockDim.x) {
        float4 v = p4[q];
        long base = q * 4;
        float vals[4] = {v.x, v.y, v.z, v.w};
        #pragma unroll
        for (int c = 0; c < 4; ++c) {
            if (vals[c] != 0.0f) {
                long i = base + c;
                int f = (int)(i >> 12);          // / D_IN
                int d = (int)(i & (D_IN - 1));   // % D_IN
                int slot = atomicAdd(&col_cnt[d], 1);
                if (slot < 4) {
                    col_f[d * 4 + slot] = f;
                    col_v[d * 4 + slot] = vals[c];
                }
            }
        }
    }
}

// Canonicalize: sort each column's 4 entries by f (makes structure deterministic).
__global__ void k_sortcol(int* __restrict__ col_f, float* __restrict__ col_v) {
    int d = blockIdx.x * blockDim.x + threadIdx.x;
    if (d >= D_IN) return;
    int f0 = col_f[d*4+0], f1 = col_f[d*4+1], f2 = col_f[d*4+2], f3 = col_f[d*4+3];
    float v0 = col_v[d*4+0], v1 = col_v[d*4+1], v2 = col_v[d*4+2], v3 = col_v[d*4+3];
    int tf; float tv;
    #define CSWAP(a,b,va,vb) if (a > b) { tf=a; a=b; b=tf; tv=va; va=vb; vb=tv; }
    CSWAP(f0,f1,v0,v1); CSWAP(f2,f3,v2,v3);
    CSWAP(f0,f2,v0,v2); CSWAP(f1,f3,v1,v3);
    CSWAP(f1,f2,v1,v2);
    #undef CSWAP
    col_f[d*4+0]=f0; col_f[d*4+1]=f1; col_f[d*4+2]=f2; col_f[d*4+3]=f3;
    col_v[d*4+0]=v0; col_v[d*4+1]=v1; col_v[d*4+2]=v2; col_v[d*4+3]=v3;
}

// Bin column entries into row lists.
__global__ void k_bin(const int* __restrict__ col_f, const float* __restrict__ col_v,
                      int* __restrict__ row_cnt, int2* __restrict__ row_ent) {
    int e = blockIdx.x * blockDim.x + threadIdx.x;
    if (e >= D_IN * 4) return;
    int d = e >> 2;
    int f = col_f[e];
    float v = col_v[e];
    int slot = atomicAdd(&row_cnt[f], 1);
    if (slot < CAP) row_ent[f * CAP + slot] = make_int2(d, __float_as_int(v));
}

// Canonicalize: sort each row's entries by d (deterministic sum order).
__global__ void k_sortrow(int* __restrict__ row_cnt, int2* __restrict__ row_ent) {
    int f = blockIdx.x * blockDim.x + threadIdx.x;
    if (f >= D_FEAT) return;
    int cnt = row_cnt[f];
    if (cnt > CAP) { cnt = CAP; row_cnt[f] = CAP; }
    // in-place insertion sort in global memory (tiny one-shot kernel; perf irrelevant)
    for (int a = 1; a < cnt; ++a) {
        int2 key = row_ent[f * CAP + a];
        int b = a - 1;
        while (b >= 0) {
            int2 cur = row_ent[f * CAP + b];
            if (cur.x <= key.x) break;
            row_ent[f * CAP + b + 1] = cur;
            --b;
        }
        row_ent[f * CAP + b + 1] = key;
    }
}

// Main gather: 4 x-rows per block staged interleaved in LDS (xs[d*4+r]),
// one ds_read_b128 yields all 4 rows' x[d]. Coalesced f-major output stores.
__global__ __launch_bounds__(256) void k_gather(const float* __restrict__ x,
                                                const int* __restrict__ row_cnt,
                                                const int2* __restrict__ row_ent,
                                                float* __restrict__ out) {
    __shared__ float xs[D_IN * NR];   // 64 KB
    const int n0 = blockIdx.x * NR;
    const int tid = threadIdx.x;

    // Load 4 rows, interleaved by row: xs[d*4+r] = x[n0+r][d].
    // Global pattern: per wave, 16 consecutive d x 4 rows = 4x 64B segments.
    // LDS writes are fully sequential (conflict-free).
    for (int idx = tid; idx < D_IN * NR; idx += 256) {
        int r = idx & (NR - 1);
        int d = idx >> 2;
        xs[idx] = x[(size_t)(n0 + r) * D_IN + d];
    }
    __syncthreads();

    const float4* xs4 = (const float4*)xs;
    for (int f = tid; f < D_FEAT; f += 256) {
        int cnt = row_cnt[f];
        if (cnt > CAP) cnt = CAP;
        const int2* e = &row_ent[(size_t)f * CAP];
        float ax = 0.f, ay = 0.f, az = 0.f, aw = 0.f;
        for (int j = 0; j < cnt; ++j) {
            int2 ev = e[j];
            float val = __int_as_float(ev.y);
            float4 xv = xs4[ev.x];
            ax += xv.x * val;
            ay += xv.y * val;
            az += xv.z * val;
            aw += xv.w * val;
        }
        out[(size_t)(n0 + 0) * D_FEAT + f] = ax;
        out[(size_t)(n0 + 1) * D_FEAT + f] = ay;
        out[(size_t)(n0 + 2) * D_FEAT + f] = az;
        out[(size_t)(n0 + 3) * D_FEAT + f] = aw;
    }
}

extern "C" void kernel_launch(void* const* d_in, const int* in_sizes, int n_in,
                              void* d_out, int out_size, void* d_ws, size_t ws_size,
                              hipStream_t stream) {
    const float* x = (const float*)d_in[0];
    const float* P = (const float*)d_in[1];
    float* out = (float*)d_out;

    char* ws = (char*)d_ws;
    int*   col_f   = (int*)  (ws + 0);
    float* col_v   = (float*)(ws + 65536);
    int*   col_cnt = (int*)  (ws + 131072);
    int*   row_cnt = (int*)  (ws + 147456);
    int2*  row_ent = (int2*) (ws + 180224);

    k_zero   <<<(D_FEAT + 255) / 256, 256, 0, stream>>>(col_cnt, row_cnt);
    k_scan   <<<2048, 256, 0, stream>>>((const float4*)P, col_cnt, col_f, col_v);
    k_sortcol<<<(D_IN + 255) / 256, 256, 0, stream>>>(col_f, col_v);
    k_bin    <<<(D_IN * 4 + 255) / 256, 256, 0, stream>>>(col_f, col_v, row_cnt, row_ent);
    k_sortrow<<<(D_FEAT + 255) / 256, 256, 0, stream>>>(row_cnt, row_ent);
    k_gather <<<N_TOTAL / NR, 256, 0, stream>>>(x, row_cnt, row_ent, out);
}

// Round 3
// 304.579 us; speedup vs baseline: 1.6724x; 1.6724x over previous
//
#include <hip/hip_runtime.h>

// OSNAP sketch: out[n,f] = sum_d x[n,d] * P[f,d]
// x: [16384,4096] f32. P: [8192,4096] f32, exactly 4 nonzeros (+-0.5) per COLUMN.
// => exactly 16384 nonzeros; each output row f has Poisson(2)-distributed nnz.
// Structure extracted per launch into d_ws, then a fixed-4-entry gather kernel.

#define D_IN    4096
#define D_FEAT  8192
#define N_TOT   16384
#define CAP     16        // per-row clamp (P(Poisson(2) >= 16) ~ 4e-10 per row)
#define NR      4         // x-rows per gather block
#define OVF_CAP 16384

// ---------------- ws layout (bytes, NO overlaps) ----------------
// 0        col_f    int  [D_IN*4]      65536
// 65536    col_v    float[D_IN*4]      65536   -> 131072
// 131072   col_cnt  int  [D_IN]        16384   -> 147456
// 147456   row_cnt  int  [D_FEAT]      32768   -> 180224
// 180224   row_ent  int2 [D_FEAT*CAP]  1048576 -> 1228800   (.x=d, .y=bits(val))
// 1228800  ent4     int4 [D_FEAT]      131072  -> 1359872   (4 packed entries/row)
// 1359872  ovf_desc int  [D_FEAT]      32768   -> 1392640   ((start<<5)|extra)
// 1392640  ovf_ents int  [OVF_CAP]     65536   -> 1458176
// total ~1.46 MB (< 1.72 MB footprint that round 1 proved works)

__global__ void k_zero(int* __restrict__ col_cnt, int* __restrict__ row_cnt) {
    int t = blockIdx.x * blockDim.x + threadIdx.x;
    if (t < D_IN)   col_cnt[t] = 0;
    if (t < D_FEAT) row_cnt[t] = 0;
}

// Full-BW scan of P (128MB): append each column's 4 nonzeros.
__global__ void k_scan(const float4* __restrict__ p4,
                       int* __restrict__ col_cnt,
                       int* __restrict__ col_f,
                       float* __restrict__ col_v) {
    const long total = (long)D_FEAT * D_IN / 4;
    for (long q = (long)blockIdx.x * blockDim.x + threadIdx.x; q < total;
         q += (long)gridDim.x * blockDim.x) {
        float4 v = p4[q];
        long base = q * 4;
        float vals[4] = {v.x, v.y, v.z, v.w};
        #pragma unroll
        for (int c = 0; c < 4; ++c) {
            if (vals[c] != 0.0f) {
                long i = base + c;
                int f = (int)(i >> 12);          // / D_IN
                int d = (int)(i & (D_IN - 1));   // % D_IN
                int slot = atomicAdd(&col_cnt[d], 1);
                if (slot < 4) {
                    col_f[d * 4 + slot] = f;
                    col_v[d * 4 + slot] = vals[c];
                }
            }
        }
    }
}

// Bin column entries into per-row lists (order canonicalized by k_sortrow).
__global__ void k_bin(const int* __restrict__ col_f, const float* __restrict__ col_v,
                      int* __restrict__ row_cnt, int2* __restrict__ row_ent) {
    int e = blockIdx.x * blockDim.x + threadIdx.x;
    if (e >= D_IN * 4) return;
    int d = e >> 2;
    int f = col_f[e];
    float v = col_v[e];
    int slot = atomicAdd(&row_cnt[f], 1);
    if (slot < CAP) row_ent[f * CAP + slot] = make_int2(d, __float_as_int(v));
}

// Sort each row's entries by d (d distinct within a row) -> deterministic.
__global__ void k_sortrow(int* __restrict__ row_cnt, int2* __restrict__ row_ent) {
    int f = blockIdx.x * blockDim.x + threadIdx.x;
    if (f >= D_FEAT) return;
    int cnt = row_cnt[f];
    if (cnt > CAP) { cnt = CAP; row_cnt[f] = CAP; }
    for (int a = 1; a < cnt; ++a) {
        int2 key = row_ent[f * CAP + a];
        int b = a - 1;
        while (b >= 0) {
            int2 cur = row_ent[f * CAP + b];
            if (cur.x <= key.x) break;
            row_ent[f * CAP + b + 1] = cur;
            --b;
        }
        row_ent[f * CAP + b + 1] = key;
    }
}

// Exclusive prefix sum of per-row overflow counts (single block).
__global__ __launch_bounds__(256) void k_ovfscan(const int* __restrict__ row_cnt,
                                                 int* __restrict__ ovf_desc) {
    __shared__ int partial[256];
    const int tid = threadIdx.x;
    const int base = tid * 32;
    int extras[32];
    int sum = 0;
    #pragma unroll
    for (int j = 0; j < 32; ++j) {
        int c = row_cnt[base + j];
        if (c > CAP) c = CAP;
        int ex = (c > 4) ? (c - 4) : 0;
        extras[j] = ex;
        sum += ex;
    }
    partial[tid] = sum;
    __syncthreads();
    for (int s = 1; s < 256; s <<= 1) {
        int v = (tid >= s) ? partial[tid - s] : 0;
        __syncthreads();
        partial[tid] += v;
        __syncthreads();
    }
    int run = (tid == 0) ? 0 : partial[tid - 1];   // exclusive prefix
    #pragma unroll
    for (int j = 0; j < 32; ++j) {
        int st = run;
        if (st > OVF_CAP - 32) st = OVF_CAP - 32;  // capacity guard
        ovf_desc[base + j] = (st << 5) | extras[j];
        run += extras[j];
    }
}

// Pack: first 4 entries -> int4 (entry = d*16 | sign<<31; dummy = D_IN*16 -> zero
// LDS slot; bit30 of .w = "has overflow"); extras -> compact ovf_ents.
__global__ void k_pack(const int* __restrict__ row_cnt, const int2* __restrict__ row_ent,
                       const int* __restrict__ ovf_desc,
                       int4* __restrict__ ent4, int* __restrict__ ovf_ents) {
    int f = blockIdx.x * blockDim.x + threadIdx.x;
    if (f >= D_FEAT) return;
    int cnt = row_cnt[f];
    int e[4];
    #pragma unroll
    for (int j = 0; j < 4; ++j) {
        if (j < cnt) {
            int2 ev = row_ent[f * CAP + j];
            e[j] = (ev.x * 16) | (int)((unsigned)ev.y & 0x80000000u);
        } else {
            e[j] = D_IN * 16;   // dummy -> zeroed LDS slot
        }
    }
    if (cnt > 4) e[3] |= 0x40000000;
    ent4[f] = make_int4(e[0], e[1], e[2], e[3]);
    int od = ovf_desc[f];
    int start = od >> 5;
    // defensive clamp: even a corrupt descriptor cannot write outside ovf_ents
    if (start < 0) start = 0;
    if (start > OVF_CAP - 32) start = OVF_CAP - 32;
    for (int j = 4; j < cnt; ++j) {
        int2 ev = row_ent[f * CAP + j];
        ovf_ents[start + j - 4] = (ev.x * 16) | (int)((unsigned)ev.y & 0x80000000u);
    }
}

// Main gather: 4 x-rows interleaved in LDS (xs[d*4+r]); one ds_read_b128 per
// entry serves 4 output rows. Uniform 4-entry inner loop, sign applied by XOR.
__global__ __launch_bounds__(512) void k_gather(const float* __restrict__ x,
                                                const int4* __restrict__ ent4,
                                                const int* __restrict__ ovf_desc,
                                                const int* __restrict__ ovf_ents,
                                                float* __restrict__ out) {
    __shared__ float xs[D_IN * NR + 4];   // +4: zero slot for dummy entries
    const int n0 = blockIdx.x * NR;
    const int tid = threadIdx.x;

    // Stage rows n0..n0+3 interleaved: xs[d*4+r] = x[n0+r][d].
    // Sequential LDS writes (conflict-free); global reads: 4x 64B segs/wave.
    for (int idx = tid; idx < D_IN * NR; idx += 512) {
        int r = idx & (NR - 1);
        int d = idx >> 2;
        xs[idx] = x[(size_t)(n0 + r) * D_IN + d];
    }
    if (tid == 0) {
        xs[D_IN * 4 + 0] = 0.f; xs[D_IN * 4 + 1] = 0.f;
        xs[D_IN * 4 + 2] = 0.f; xs[D_IN * 4 + 3] = 0.f;
    }
    __syncthreads();

    const char* xsb = (const char*)xs;
    float* o0 = out + (size_t)n0 * D_FEAT;
    float* o1 = o0 + D_FEAT;
    float* o2 = o1 + D_FEAT;
    float* o3 = o2 + D_FEAT;

    #pragma unroll 2
    for (int f = tid; f < D_FEAT; f += 512) {
        int4 e = ent4[f];
        float a0 = 0.f, a1 = 0.f, a2 = 0.f, a3 = 0.f;
        #define ENTRY(EE) { \
            const float4 xv = *(const float4*)(xsb + ((EE) & 0x1FFF0)); \
            unsigned sgn = (unsigned)(EE) & 0x80000000u; \
            a0 += __uint_as_float(__float_as_uint(xv.x) ^ sgn); \
            a1 += __uint_as_float(__float_as_uint(xv.y) ^ sgn); \
            a2 += __uint_as_float(__float_as_uint(xv.z) ^ sgn); \
            a3 += __uint_as_float(__float_as_uint(xv.w) ^ sgn); }
        ENTRY(e.x) ENTRY(e.y) ENTRY(e.z) ENTRY(e.w)
        #undef ENTRY
        if (e.w & 0x40000000) {            // rare (~5% of rows): overflow tail
            int od = ovf_desc[f];
            int extra = od & 31;
            const int* oe = ovf_ents + (od >> 5);
            for (int j = 0; j < extra; ++j) {
                int ee = oe[j];
                const float4 xv = *(const float4*)(xsb + (ee & 0x1FFF0));
                unsigned sgn = (unsigned)ee & 0x80000000u;
                a0 += __uint_as_float(__float_as_uint(xv.x) ^ sgn);
                a1 += __uint_as_float(__float_as_uint(xv.y) ^ sgn);
                a2 += __uint_as_float(__float_as_uint(xv.z) ^ sgn);
                a3 += __uint_as_float(__float_as_uint(xv.w) ^ sgn);
            }
        }
        o0[f] = a0 * 0.5f;
        o1[f] = a1 * 0.5f;
        o2[f] = a2 * 0.5f;
        o3[f] = a3 * 0.5f;
    }
}

extern "C" void kernel_launch(void* const* d_in, const int* in_sizes, int n_in,
                              void* d_out, int out_size, void* d_ws, size_t ws_size,
                              hipStream_t stream) {
    const float* x = (const float*)d_in[0];
    const float* P = (const float*)d_in[1];
    float* out = (float*)d_out;

    char* ws = (char*)d_ws;
    int*   col_f    = (int*)  (ws + 0);
    float* col_v    = (float*)(ws + 65536);
    int*   col_cnt  = (int*)  (ws + 131072);
    int*   row_cnt  = (int*)  (ws + 147456);
    int2*  row_ent  = (int2*) (ws + 180224);
    int4*  ent4     = (int4*) (ws + 1228800);
    int*   ovf_desc = (int*)  (ws + 1359872);
    int*   ovf_ents = (int*)  (ws + 1392640);

    k_zero   <<<(D_FEAT + 255) / 256, 256, 0, stream>>>(col_cnt, row_cnt);
    k_scan   <<<2048, 256, 0, stream>>>((const float4*)P, col_cnt, col_f, col_v);
    k_bin    <<<(D_IN * 4 + 255) / 256, 256, 0, stream>>>(col_f, col_v, row_cnt, row_ent);
    k_sortrow<<<(D_FEAT + 255) / 256, 256, 0, stream>>>(row_cnt, row_ent);
    k_ovfscan<<<1, 256, 0, stream>>>(row_cnt, ovf_desc);
    k_pack   <<<(D_FEAT + 255) / 256, 256, 0, stream>>>(row_cnt, row_ent, ovf_desc, ent4, ovf_ents);
    k_gather <<<N_TOT / NR, 512, 0, stream>>>(x, ent4, ovf_desc, ovf_ents, out);
}